// Round 1
// baseline (609.684 us; speedup 1.0000x reference)
//
#include <hip/hip_runtime.h>
#include <hip/hip_bf16.h>

#define KT    16
#define NPER  16384
#define DIN   256
#define DOUT  256
#define NTOT  (KT * NPER)

typedef __attribute__((ext_vector_type(8))) short  short8;
typedef __attribute__((ext_vector_type(4))) float  f32x4;
typedef __attribute__((ext_vector_type(4))) unsigned int uint32x4;

// fp32 bits -> bf16 bits, round-to-nearest-even (no NaN in this data)
__device__ __forceinline__ unsigned int bfbits(unsigned int u) {
    return (u + 0x7fffu + ((u >> 16) & 1u)) >> 16;
}

// pack 8 consecutive fp32 (raw bits) -> 8 bf16 (RNE), memory order preserved
__device__ __forceinline__ short8 pack8(uint32x4 a, uint32x4 b) {
    uint32x4 r;
    r.x = bfbits(a.x) | (bfbits(a.y) << 16);
    r.y = bfbits(a.z) | (bfbits(a.w) << 16);
    r.z = bfbits(b.x) | (bfbits(b.y) << 16);
    r.w = bfbits(b.z) | (bfbits(b.w) << 16);
    short8 s;
    __builtin_memcpy(&s, &r, sizeof(s));
    return s;
}

__device__ __forceinline__ unsigned short f2bf(float f) {
    return (unsigned short)bfbits(__float_as_uint(f));
}

// tanh(y) = sign(y) * (1 - t) / (1 + t),  t = exp(-2|y|)  (stable, no overflow)
__device__ __forceinline__ float fast_tanh(float y) {
    float a = fabsf(y);
    float t = __expf(-2.0f * a);
    float r = (1.0f - t) * __builtin_amdgcn_rcpf(1.0f + t);
    return copysignf(r, y);
}

// ---- prep kernels -----------------------------------------------------------

__global__ void prep_w(const float* __restrict__ w, unsigned short* __restrict__ wbf) {
    int i = blockIdx.x * blockDim.x + threadIdx.x;    // 262144 float4 groups
    float4 v = ((const float4*)w)[i];
    unsigned int p0 = (unsigned int)f2bf(v.x) | ((unsigned int)f2bf(v.y) << 16);
    unsigned int p1 = (unsigned int)f2bf(v.z) | ((unsigned int)f2bf(v.w) << 16);
    ((uint2*)wbf)[i] = make_uint2(p0, p1);
}

__global__ void prep_inv(const int* __restrict__ perm, int* __restrict__ inv) {
    int i = blockIdx.x * blockDim.x + threadIdx.x;    // NTOT threads
    inv[perm[i]] = i;
}

// ---- main GEMM + scatter + tanh --------------------------------------------
// LDS-FREE structure. Block = 128 rows x 256 cols of one type, 512 threads
// (8 waves, wave tile 64x64 as (wm,wn) = 2x4 — identical fragment/output
// mapping to the previously verified kernel).
//
// A fragment: 32 B/lane straight from global x (two dwordx4, full 128B lines,
//   K-window fully consumed) + in-register fp32->bf16 pack. x4 wn-redundancy
//   is L1/L2-served (32 KiB per-stage set).
// B fragment: 16 B/lane gather from wbf — 2 MiB total, L2-resident.
// No LDS => no __syncthreads => no vmcnt(0) drains: the read/write streams
// run continuously and the compiler pipelines across all 8 K-steps.

__launch_bounds__(512, 4)
__global__ void gemm_scatter(const float* __restrict__ x,
                             const unsigned short* __restrict__ wbf,
                             const int* __restrict__ inv,
                             float* __restrict__ out) {
    const int tid  = threadIdx.x;
    const int bid  = blockIdx.x;
    const int kt   = bid >> 7;          // 16 types
    const int rt   = bid & 127;         // 128 row tiles per type

    const int lane = tid & 63;
    const int wv   = tid >> 6;     // 0..7
    const int wm   = wv & 1;       // row half (0..1)
    const int wn   = wv >> 1;      // col quarter (0..3)
    const int lo   = lane & 15;
    const int hi   = lane >> 4;

    const int rowbase = rt * 128;

    // per-lane fragment base pointers
    const float* xb = x
        + ((size_t)(kt * NPER + rowbase + wm * 64 + lo)) * DIN + hi * 8;
    const unsigned short* wb = wbf
        + (size_t)kt * DOUT * DIN + (size_t)(wn * 64 + lo) * DIN + hi * 8;

    f32x4 acc[4][4];
#pragma unroll
    for (int i = 0; i < 4; i++)
#pragma unroll
        for (int j = 0; j < 4; j++) acc[i][j] = (f32x4){0.f, 0.f, 0.f, 0.f};

#pragma unroll
    for (int kk = 0; kk < 8; ++kk) {
        const int k0 = kk * 32;

        short8 af[4], bf[4];
#pragma unroll
        for (int i = 0; i < 4; ++i) {
            const uint32x4* p = (const uint32x4*)(xb + (size_t)(i * 16) * DIN + k0);
            uint32x4 v0 = p[0];
            uint32x4 v1 = p[1];
            af[i] = pack8(v0, v1);
        }
#pragma unroll
        for (int j = 0; j < 4; ++j)
            bf[j] = *(const short8*)(wb + (size_t)(j * 16) * DIN + k0);

#pragma unroll
        for (int i = 0; i < 4; ++i)
#pragma unroll
            for (int j = 0; j < 4; ++j)
                acc[i][j] = __builtin_amdgcn_mfma_f32_16x16x32_bf16(
                    af[i], bf[j], acc[i][j], 0, 0, 0);
    }

    // epilogue: tanh + permuted row scatter.
    // C/D layout: col = lane&15, row = (lane>>4)*4 + reg   [measured m89/m91]
#pragma unroll
    for (int i = 0; i < 4; ++i) {
        const int4 iv = *(const int4*)&inv[kt * NPER + rowbase + wm * 64 + i * 16 + hi * 4];
        const int orow[4] = {iv.x, iv.y, iv.z, iv.w};
#pragma unroll
        for (int r = 0; r < 4; ++r) {
            float* op = out + (size_t)orow[r] * DOUT + wn * 64 + lo;
#pragma unroll
            for (int j = 0; j < 4; ++j)
                op[j * 16] = fast_tanh(acc[i][j][r]);
        }
    }
}

// ---- launch -----------------------------------------------------------------

extern "C" void kernel_launch(void* const* d_in, const int* in_sizes, int n_in,
                              void* d_out, int out_size, void* d_ws, size_t ws_size,
                              hipStream_t stream) {
    const float* x    = (const float*)d_in[0];   // [16,16384,256] fp32
    const float* w    = (const float*)d_in[1];   // [16,256,256]  fp32
    const int*   perm = (const int*)d_in[2];     // [262144]      int32
    float*       out  = (float*)d_out;           // [262144,256]  fp32

    unsigned short* wbf = (unsigned short*)d_ws;                         // 2 MiB
    int*            inv = (int*)((char*)d_ws + (size_t)2 * 1024 * 1024); // 1 MiB

    prep_w  <<<1024, 256, 0, stream>>>(w, wbf);      // 16*256*256/4 float4s
    prep_inv<<<1024, 256, 0, stream>>>(perm, inv);   // NTOT threads
    gemm_scatter<<<KT * 128, 512, 0, stream>>>(x, wbf, inv, out);
}

// Round 2
// 525.430 us; speedup vs baseline: 1.1604x; 1.1604x over previous
//
#include <hip/hip_runtime.h>

#define KT    16
#define NPER  16384
#define DIN   256
#define DOUT  256

#define BK      32          // K-slice per stage
#define NSTAGE  8           // 256 / 32
#define LSTRIDE 40          // shorts per LDS row: 80 B = 5x16B (gload-lds integral,
                            // 16B-aligned rows, conflict-free b128 reads)

typedef __attribute__((ext_vector_type(8))) short  short8;
typedef __attribute__((ext_vector_type(4))) float  f32x4;
typedef __attribute__((ext_vector_type(4))) unsigned int uint32x4;

// fp32 bits -> bf16 bits, round-to-nearest-even (no NaN in this data)
__device__ __forceinline__ unsigned int bfbits(unsigned int u) {
    return (u + 0x7fffu + ((u >> 16) & 1u)) >> 16;
}
__device__ __forceinline__ unsigned short f2bf(float f) {
    return (unsigned short)bfbits(__float_as_uint(f));
}

// tanh(y) = sign(y) * (1 - t) / (1 + t),  t = exp(-2|y|)  (stable, no overflow)
__device__ __forceinline__ float fast_tanh(float y) {
    float a = fabsf(y);
    float t = __expf(-2.0f * a);
    float r = (1.0f - t) * __builtin_amdgcn_rcpf(1.0f + t);
    return copysignf(r, y);
}

// async global->LDS, 16 B per lane, dest = uniform base + lane*16
#define GLDS16(gsrc, ldst)                                                        \
    __builtin_amdgcn_global_load_lds(                                             \
        (const __attribute__((address_space(1))) void*)(gsrc),                    \
        (__attribute__((address_space(3))) void*)(ldst), 16, 0, 0)

// ---- prep kernels -----------------------------------------------------------

__global__ void prep_w(const float* __restrict__ w, unsigned short* __restrict__ wbf) {
    int i = blockIdx.x * blockDim.x + threadIdx.x;    // 262144 float4 groups
    float4 v = ((const float4*)w)[i];
    unsigned int p0 = (unsigned int)f2bf(v.x) | ((unsigned int)f2bf(v.y) << 16);
    unsigned int p1 = (unsigned int)f2bf(v.z) | ((unsigned int)f2bf(v.w) << 16);
    ((uint2*)wbf)[i] = make_uint2(p0, p1);
}

__global__ void prep_inv(const int* __restrict__ perm, int* __restrict__ inv) {
    int i = blockIdx.x * blockDim.x + threadIdx.x;    // NTOT threads
    inv[perm[i]] = i;
}

// ---- main GEMM + scatter + tanh --------------------------------------------
// Block tile 128x256, 512 threads (8 waves, wave tile 64x64 as (wm,wn)=2x4).
// BK=32 double-buffered pipeline, ONE barrier per stage:
//   stage s: issue A loads(s+1) -> regs, issue B gload_lds(s+1) -> buf^1,
//            ds_read+MFMA on buf, cvt+ds_write A(s+1), barrier.
// B goes global->LDS directly (already bf16): zero staging VGPRs.
// A is fp32 and needs cvt, so it reg-stages (T14 issue-early/write-late).

__launch_bounds__(512, 4)
__global__ void gemm_scatter(const float* __restrict__ x,
                             const unsigned short* __restrict__ wbf,
                             const int* __restrict__ inv,
                             float* __restrict__ out) {
    __shared__ unsigned short aLds[2][128 * LSTRIDE];   // 2 x 10 KiB
    __shared__ unsigned short bLds[2][256 * LSTRIDE];   // 2 x 20 KiB
    __shared__ int invLds[128];

    const int tid = threadIdx.x;
    const int bid = blockIdx.x;
    const int kt  = bid >> 7;          // 16 types
    const int rt  = bid & 127;         // 128 row tiles per type

    const float*          xblk = x   + (size_t)(kt * NPER + rt * 128) * DIN;
    const unsigned short* wblk = wbf + (size_t)kt * DOUT * DIN;

    if (tid < 128) invLds[tid] = inv[kt * NPER + rt * 128 + tid];

    const int lane = tid & 63;
    const int wv   = tid >> 6;     // 0..7
    const int wm   = wv & 1;       // row half (0..1)
    const int wn   = wv >> 1;      // col quarter (0..3)
    const int lo   = lane & 15;
    const int hi   = lane >> 4;

    // A staging geometry: 128 rows x 32 fp32 per stage = 512 chunks of 8 floats
    const int arow = tid >> 2;     // 0..127
    const int ac8  = tid & 3;      // 0..3
    const float* aSrc = xblk + (size_t)arow * DIN + ac8 * 8;
    const int    aOff = arow * LSTRIDE + ac8 * 8;     // shorts

    // B staging geometry: 256 rows x 80 B = 20 KiB = 20 chunks of 1 KiB.
    // wave w stages chunks {2w, 2w+1}; waves 0-3 also stage {16+w}.
    // lane l of chunk c covers linear bytes c*1024 + l*16 of the [256][80B] buf.
    const int c0 = wv * 2, c1 = c0 + 1, c2 = 16 + wv;
    const int b0 = c0 * 1024 + lane * 16;
    const int b1 = c1 * 1024 + lane * 16;
    const int b2 = c2 * 1024 + lane * 16;
    // (pad cols 32..39 fetch harmless in-bounds garbage; never read back)
    const unsigned short* bSrc0 = wblk + (size_t)(b0 / 80) * DIN + (b0 % 80) / 2;
    const unsigned short* bSrc1 = wblk + (size_t)(b1 / 80) * DIN + (b1 % 80) / 2;
    const unsigned short* bSrc2 = wblk + (size_t)(b2 / 80) * DIN + (b2 % 80) / 2;
    const int bo0 = c0 * 512, bo1 = c1 * 512, bo2 = c2 * 512;  // dest, shorts

    f32x4 acc[4][4];
#pragma unroll
    for (int i = 0; i < 4; i++)
#pragma unroll
        for (int j = 0; j < 4; j++) acc[i][j] = (f32x4){0.f, 0.f, 0.f, 0.f};

    // ---- prologue: stage 0 into buffer 0
    {
        float4 a0 = ((const float4*)aSrc)[0];
        float4 a1 = ((const float4*)aSrc)[1];
        GLDS16(bSrc0, &bLds[0][bo0]);
        GLDS16(bSrc1, &bLds[0][bo1]);
        if (wv < 4) GLDS16(bSrc2, &bLds[0][bo2]);
        uint32x4 pk;
        pk.x = bfbits(__float_as_uint(a0.x)) | (bfbits(__float_as_uint(a0.y)) << 16);
        pk.y = bfbits(__float_as_uint(a0.z)) | (bfbits(__float_as_uint(a0.w)) << 16);
        pk.z = bfbits(__float_as_uint(a1.x)) | (bfbits(__float_as_uint(a1.y)) << 16);
        pk.w = bfbits(__float_as_uint(a1.z)) | (bfbits(__float_as_uint(a1.w)) << 16);
        *(uint32x4*)&aLds[0][aOff] = pk;
    }
    __syncthreads();   // drains vmcnt: buffer 0 fully staged

    for (int s = 0; s < NSTAGE; ++s) {
        const int cur = s & 1;

        // issue next stage's loads first: A -> regs, B -> LDS (other buffer)
        float4 a0, a1;
        if (s < NSTAGE - 1) {
            const int d0n = (s + 1) * BK;
            a0 = ((const float4*)(aSrc + d0n))[0];
            a1 = ((const float4*)(aSrc + d0n))[1];
            GLDS16(bSrc0 + d0n, &bLds[cur ^ 1][bo0]);
            GLDS16(bSrc1 + d0n, &bLds[cur ^ 1][bo1]);
            if (wv < 4) GLDS16(bSrc2 + d0n, &bLds[cur ^ 1][bo2]);
        }

        // compute current buffer
        short8 af[4], bfr[4];
#pragma unroll
        for (int i = 0; i < 4; i++)
            af[i] = *(const short8*)&aLds[cur][(wm * 64 + i * 16 + lo) * LSTRIDE + hi * 8];
#pragma unroll
        for (int j = 0; j < 4; j++)
            bfr[j] = *(const short8*)&bLds[cur][(wn * 64 + j * 16 + lo) * LSTRIDE + hi * 8];
#pragma unroll
        for (int i = 0; i < 4; i++)
#pragma unroll
            for (int j = 0; j < 4; j++)
                acc[i][j] = __builtin_amdgcn_mfma_f32_16x16x32_bf16(
                    af[i], bfr[j], acc[i][j], 0, 0, 0);

        // late half of the A stage: cvt + ds_write into the other buffer
        if (s < NSTAGE - 1) {
            uint32x4 pk;
            pk.x = bfbits(__float_as_uint(a0.x)) | (bfbits(__float_as_uint(a0.y)) << 16);
            pk.y = bfbits(__float_as_uint(a0.z)) | (bfbits(__float_as_uint(a0.w)) << 16);
            pk.z = bfbits(__float_as_uint(a1.x)) | (bfbits(__float_as_uint(a1.y)) << 16);
            pk.w = bfbits(__float_as_uint(a1.z)) | (bfbits(__float_as_uint(a1.w)) << 16);
            *(uint32x4*)&aLds[cur ^ 1][aOff] = pk;
        }
        __syncthreads();   // one barrier per stage: buf^1 staged, buf reads done
    }

    // epilogue: tanh + permuted row scatter.
    // C/D layout: col = lane&15, row = (lane>>4)*4 + reg   [measured m89/m91]
#pragma unroll
    for (int i = 0; i < 4; i++) {
#pragma unroll
        for (int r = 0; r < 4; r++) {
            int rowL = wm * 64 + i * 16 + hi * 4 + r;
            size_t orow = (size_t)invLds[rowL];
            float* op = out + orow * DOUT;
#pragma unroll
            for (int j = 0; j < 4; j++) {
                int col = wn * 64 + j * 16 + lo;
                op[col] = fast_tanh(acc[i][j][r]);
            }
        }
    }
}

// ---- launch -----------------------------------------------------------------

extern "C" void kernel_launch(void* const* d_in, const int* in_sizes, int n_in,
                              void* d_out, int out_size, void* d_ws, size_t ws_size,
                              hipStream_t stream) {
    const float* x    = (const float*)d_in[0];   // [16,16384,256] fp32
    const float* w    = (const float*)d_in[1];   // [16,256,256]  fp32
    const int*   perm = (const int*)d_in[2];     // [262144]      int32
    float*       out  = (float*)d_out;           // [262144,256]  fp32

    unsigned short* wbf = (unsigned short*)d_ws;                         // 2 MiB
    int*            inv = (int*)((char*)d_ws + (size_t)2 * 1024 * 1024); // 1 MiB

    prep_w  <<<1024, 256, 0, stream>>>(w, wbf);      // 16*256*256/4 float4s
    prep_inv<<<1024, 256, 0, stream>>>(perm, inv);   // NTOT threads
    gemm_scatter<<<KT * 128, 512, 0, stream>>>(x, wbf, inv, out);
}

// Round 3
// 513.964 us; speedup vs baseline: 1.1862x; 1.0223x over previous
//
#include <hip/hip_runtime.h>

#define KT    16
#define NPER  16384
#define DIN   256
#define DOUT  256

#define LSTR  264    // shorts per LDS row: 528 B stride ≡ 4 dwords mod 32 banks
                     // (same conflict-free class as verified 144 B stride)

typedef __attribute__((ext_vector_type(8))) short  short8;
typedef __attribute__((ext_vector_type(4))) float  f32x4;
typedef __attribute__((ext_vector_type(4))) unsigned int uint32x4;

// fp32 bits -> bf16 bits, round-to-nearest-even (no NaN in this data)
__device__ __forceinline__ unsigned int bfbits(unsigned int u) {
    return (u + 0x7fffu + ((u >> 16) & 1u)) >> 16;
}
__device__ __forceinline__ unsigned short f2bf(float f) {
    return (unsigned short)bfbits(__float_as_uint(f));
}

// pack 8 consecutive fp32 (raw bits) -> 8 bf16 (RNE), memory order preserved
// (verified correct in round-1 kernel: same absmax as LDS path)
__device__ __forceinline__ short8 pack8(uint32x4 a, uint32x4 b) {
    uint32x4 r;
    r.x = bfbits(a.x) | (bfbits(a.y) << 16);
    r.y = bfbits(a.z) | (bfbits(a.w) << 16);
    r.z = bfbits(b.x) | (bfbits(b.y) << 16);
    r.w = bfbits(b.z) | (bfbits(b.w) << 16);
    short8 s;
    __builtin_memcpy(&s, &r, sizeof(s));
    return s;
}

// tanh(y) = sign(y) * (1 - t) / (1 + t),  t = exp(-2|y|)  (stable, no overflow)
__device__ __forceinline__ float fast_tanh(float y) {
    float a = fabsf(y);
    float t = __expf(-2.0f * a);
    float r = (1.0f - t) * __builtin_amdgcn_rcpf(1.0f + t);
    return copysignf(r, y);
}

// ---- prep kernels -----------------------------------------------------------

__global__ void prep_w(const float* __restrict__ w, unsigned short* __restrict__ wbf) {
    int i = blockIdx.x * blockDim.x + threadIdx.x;    // 262144 float4 groups
    float4 v = ((const float4*)w)[i];
    unsigned int p0 = (unsigned int)f2bf(v.x) | ((unsigned int)f2bf(v.y) << 16);
    unsigned int p1 = (unsigned int)f2bf(v.z) | ((unsigned int)f2bf(v.w) << 16);
    ((uint2*)wbf)[i] = make_uint2(p0, p1);
}

__global__ void prep_inv(const int* __restrict__ perm, int* __restrict__ inv) {
    int i = blockIdx.x * blockDim.x + threadIdx.x;    // NTOT threads
    inv[perm[i]] = i;
}

// ---- main GEMM + scatter + tanh --------------------------------------------
// Persistent-B structure: 256 blocks (1/CU), 1024 threads = 16 waves.
// Each block stages its type's FULL weight matrix (256x256 bf16, 132 KB
// padded) into LDS once, then processes 1024 rows (4 tiles of 256) with
// ZERO barrier drains in the main loop:
//   - B fragments: conflict-free ds_read_b128 from the persistent LDS image.
//   - A fragments: global->reg dwordx4 pairs + in-reg bf16 pack (round-1
//     verified addressing). 4x wn-redundancy is L1/L3-served.
//   - no __syncthreads after init: the compiler pipelines loads across all
//     8 K-steps and across row-tiles with counted vmcnt. Raw s_barrier per
//     row-tile only (phase coherence for L1 reuse; no vmcnt drain).
// Wave tile 64x64: wm = wv&3 (row quarter), wn = wv>>2 (col quarter).

__launch_bounds__(1024, 4)
__global__ void gemm_scatter(const float* __restrict__ x,
                             const unsigned short* __restrict__ wbf,
                             const int* __restrict__ inv,
                             float* __restrict__ out) {
    __shared__ unsigned short bLds[256 * LSTR];   // 135168 B

    const int tid = threadIdx.x;
    const int bid = blockIdx.x;        // 0..255
    const int kt  = bid >> 4;          // type
    const int blk = bid & 15;          // 1024-row slab within type

    const unsigned short* wblk = wbf + (size_t)kt * DOUT * DIN;

    // ---- stage full w-type into LDS (once). 8192 16B-chunks / 1024 threads.
#pragma unroll
    for (int it = 0; it < 8; ++it) {
        int c   = tid + it * 1024;
        int row = c >> 5, c8 = c & 31;
        uint32x4 v = *(const uint32x4*)(wblk + row * DIN + c8 * 8);
        *(uint32x4*)&bLds[row * LSTR + c8 * 8] = v;
    }
    __syncthreads();   // the only draining barrier in the kernel

    const int lane = tid & 63;
    const int wv   = tid >> 6;     // 0..15
    const int wm   = wv & 3;       // row quarter (0..3)
    const int wn   = wv >> 2;      // col quarter (0..3)
    const int lo   = lane & 15;
    const int hi   = lane >> 4;

    const int rowt0 = kt * NPER + blk * 1024;

    for (int rt = 0; rt < 4; ++rt) {
        const int rbase = rowt0 + rt * 256 + wm * 64;   // this wave's 64 rows
        const float* xb = x + (size_t)(rbase + lo) * DIN + hi * 8;

        f32x4 acc[4][4];
#pragma unroll
        for (int i = 0; i < 4; i++)
#pragma unroll
            for (int j = 0; j < 4; j++) acc[i][j] = (f32x4){0.f, 0.f, 0.f, 0.f};

#pragma unroll
        for (int kk = 0; kk < 8; ++kk) {
            const int k0 = kk * 32;

            short8 af[4], bfr[4];
#pragma unroll
            for (int i = 0; i < 4; ++i) {
                const uint32x4* p = (const uint32x4*)(xb + (size_t)(i * 16) * DIN + k0);
                uint32x4 v0 = p[0];
                uint32x4 v1 = p[1];
                af[i] = pack8(v0, v1);
            }
#pragma unroll
            for (int j = 0; j < 4; ++j)
                bfr[j] = *(const short8*)&bLds[(wn * 64 + j * 16 + lo) * LSTR + k0 + hi * 8];

#pragma unroll
            for (int i = 0; i < 4; ++i)
#pragma unroll
                for (int j = 0; j < 4; ++j)
                    acc[i][j] = __builtin_amdgcn_mfma_f32_16x16x32_bf16(
                        af[i], bfr[j], acc[i][j], 0, 0, 0);
        }

        // epilogue: tanh + permuted row scatter.
        // C/D layout: col = lane&15, row = (lane>>4)*4 + reg   [m89/m91]
#pragma unroll
        for (int i = 0; i < 4; ++i) {
            const int4 iv = *(const int4*)&inv[rbase + i * 16 + hi * 4];
            const int orow[4] = {iv.x, iv.y, iv.z, iv.w};
#pragma unroll
            for (int r = 0; r < 4; ++r) {
                float* op = out + (size_t)orow[r] * DOUT + wn * 64 + lo;
#pragma unroll
                for (int j = 0; j < 4; ++j)
                    op[j * 16] = fast_tanh(acc[i][j][r]);
            }
        }

        // phase-coherence only (B is read-only): raw barrier, NO vmcnt drain
        __builtin_amdgcn_s_barrier();
    }
}

// ---- launch -----------------------------------------------------------------

extern "C" void kernel_launch(void* const* d_in, const int* in_sizes, int n_in,
                              void* d_out, int out_size, void* d_ws, size_t ws_size,
                              hipStream_t stream) {
    const float* x    = (const float*)d_in[0];   // [16,16384,256] fp32
    const float* w    = (const float*)d_in[1];   // [16,256,256]  fp32
    const int*   perm = (const int*)d_in[2];     // [262144]      int32
    float*       out  = (float*)d_out;           // [262144,256]  fp32

    unsigned short* wbf = (unsigned short*)d_ws;                         // 2 MiB
    int*            inv = (int*)((char*)d_ws + (size_t)2 * 1024 * 1024); // 1 MiB

    prep_w  <<<1024, 256, 0, stream>>>(w, wbf);      // 16*256*256/4 float4s
    prep_inv<<<1024, 256, 0, stream>>>(perm, inv);   // NTOT threads
    gemm_scatter<<<256, 1024, 0, stream>>>(x, wbf, inv, out);
}

// Round 4
// 459.928 us; speedup vs baseline: 1.3256x; 1.1175x over previous
//
#include <hip/hip_runtime.h>

#define KT    16
#define NPER  16384
#define DIN   256
#define DOUT  256

#define BM    64
#define BK    64
#define LSTR  72     // shorts per LDS row (144 B) — MEASURED zero-conflict stride

typedef __attribute__((ext_vector_type(8))) short  short8;
typedef __attribute__((ext_vector_type(4))) float  f32x4;
typedef __attribute__((ext_vector_type(4))) unsigned int uint32x4;

// fp32 bits -> bf16 bits, round-to-nearest-even (no NaN in this data)
__device__ __forceinline__ unsigned int bfbits(unsigned int u) {
    return (u + 0x7fffu + ((u >> 16) & 1u)) >> 16;
}
__device__ __forceinline__ unsigned short f2bf(float f) {
    return (unsigned short)bfbits(__float_as_uint(f));
}

// tanh(y) = sign(y) * (1 - t) / (1 + t),  t = exp(-2|y|)  (stable, no overflow)
__device__ __forceinline__ float fast_tanh(float y) {
    float a = fabsf(y);
    float t = __expf(-2.0f * a);
    float r = (1.0f - t) * __builtin_amdgcn_rcpf(1.0f + t);
    return copysignf(r, y);
}

// ---- prep kernels -----------------------------------------------------------

__global__ void prep_w(const float* __restrict__ w, unsigned short* __restrict__ wbf) {
    int i = blockIdx.x * blockDim.x + threadIdx.x;    // 262144 float4 groups
    float4 v = ((const float4*)w)[i];
    unsigned int p0 = (unsigned int)f2bf(v.x) | ((unsigned int)f2bf(v.y) << 16);
    unsigned int p1 = (unsigned int)f2bf(v.z) | ((unsigned int)f2bf(v.w) << 16);
    ((uint2*)wbf)[i] = make_uint2(p0, p1);
}

__global__ void prep_inv(const int* __restrict__ perm, int* __restrict__ inv) {
    int i = blockIdx.x * blockDim.x + threadIdx.x;    // NTOT threads
    inv[perm[i]] = i;
}

// ---- main GEMM + scatter + tanh --------------------------------------------
// ROUND-0 VERIFIED STRUCTURE (single-buffered LDS staging, stride 72),
// tile shrunk 128x256 -> 64x256 so LDS = 46.3 KB -> 3 blocks/CU (24 waves/CU,
// was 16). Purpose: raise cross-block phase overlap -> HBM duty cycle.
// Wave tile 64x32 (wn = wv, 8 col slices): acc[4][2] = 32 AGPRs, leaving
// more arch regs for staging-load pipelining under the (512,6) cap.
// B tile re-reads (512 MB total) are L2-served: wbf = 2 MB, resident per XCD.

__launch_bounds__(512, 6)
__global__ void gemm_scatter(const float* __restrict__ x,
                             const unsigned short* __restrict__ wbf,
                             const int* __restrict__ inv,
                             float* __restrict__ out) {
    __shared__ unsigned short aLds[BM * LSTR];     //  9.2 KiB
    __shared__ unsigned short bLds[256 * LSTR];    // 36.9 KiB
    __shared__ int invLds[BM];

    const int tid = threadIdx.x;
    const int bid = blockIdx.x;
    const int kt  = bid >> 8;          // 16 types
    const int rt  = bid & 255;         // 256 row tiles (of 64) per type

    const float*          xblk = x   + (size_t)(kt * NPER + rt * BM) * DIN;
    const unsigned short* wblk = wbf + (size_t)kt * DOUT * DIN;

    if (tid < BM) invLds[tid] = inv[kt * NPER + rt * BM + tid];

    const int lane = tid & 63;
    const int wv   = tid >> 6;     // 0..7  -> column slice of 32
    const int lo   = lane & 15;
    const int hi   = lane >> 4;

    f32x4 acc[4][2];
#pragma unroll
    for (int i = 0; i < 4; i++)
#pragma unroll
        for (int j = 0; j < 2; j++) acc[i][j] = (f32x4){0.f, 0.f, 0.f, 0.f};

    // A staging: 64 rows x 64 fp32 = 512 chunks of 8 floats, 1 per thread
    const int arow = tid >> 3;     // 0..63
    const int ac8  = tid & 7;      // 0..7

    for (int s = 0; s < 4; ++s) {
        const int d0 = s * BK;

        // stage A: fp32 -> bf16 pack, one 8-float chunk per thread
        {
            const float4* p = (const float4*)(xblk + arow * DIN + d0 + ac8 * 8);
            float4 v0 = p[0];
            float4 v1 = p[1];
            uint32x4 pk;
            pk.x = bfbits(__float_as_uint(v0.x)) | (bfbits(__float_as_uint(v0.y)) << 16);
            pk.y = bfbits(__float_as_uint(v0.z)) | (bfbits(__float_as_uint(v0.w)) << 16);
            pk.z = bfbits(__float_as_uint(v1.x)) | (bfbits(__float_as_uint(v1.y)) << 16);
            pk.w = bfbits(__float_as_uint(v1.z)) | (bfbits(__float_as_uint(v1.w)) << 16);
            *(uint32x4*)&aLds[arow * LSTR + ac8 * 8] = pk;
        }
        // stage B: 256 rows x 64 bf16 = 2048 chunks of 8 bf16, 4 per thread
#pragma unroll
        for (int r8 = 0; r8 < 4; r8++) {
            int idx = tid + r8 * 512;
            int row = idx >> 3, c8 = idx & 7;
            uint32x4 v = *(const uint32x4*)(wblk + row * DIN + d0 + c8 * 8);
            *(uint32x4*)&bLds[row * LSTR + c8 * 8] = v;
        }
        __syncthreads();

#pragma unroll
        for (int ks = 0; ks < 2; ++ks) {
            const int k0 = ks * 32;
            short8 af[4], bfr[2];
#pragma unroll
            for (int i = 0; i < 4; i++)
                af[i] = *(const short8*)&aLds[(i * 16 + lo) * LSTR + k0 + hi * 8];
#pragma unroll
            for (int j = 0; j < 2; j++)
                bfr[j] = *(const short8*)&bLds[(wv * 32 + j * 16 + lo) * LSTR + k0 + hi * 8];
#pragma unroll
            for (int i = 0; i < 4; i++)
#pragma unroll
                for (int j = 0; j < 2; j++)
                    acc[i][j] = __builtin_amdgcn_mfma_f32_16x16x32_bf16(
                        af[i], bfr[j], acc[i][j], 0, 0, 0);
        }
        __syncthreads();
    }

    // epilogue: tanh + permuted row scatter.
    // C/D layout: col = lane&15, row = (lane>>4)*4 + reg   [measured m89/m91]
#pragma unroll
    for (int i = 0; i < 4; i++) {
#pragma unroll
        for (int r = 0; r < 4; r++) {
            int rowL = i * 16 + hi * 4 + r;
            size_t orow = (size_t)invLds[rowL];
            float* op = out + orow * DOUT + wv * 32 + lo;
#pragma unroll
            for (int j = 0; j < 2; j++)
                op[j * 16] = fast_tanh(acc[i][j][r]);
        }
    }
}

// ---- launch -----------------------------------------------------------------

extern "C" void kernel_launch(void* const* d_in, const int* in_sizes, int n_in,
                              void* d_out, int out_size, void* d_ws, size_t ws_size,
                              hipStream_t stream) {
    const float* x    = (const float*)d_in[0];   // [16,16384,256] fp32
    const float* w    = (const float*)d_in[1];   // [16,256,256]  fp32
    const int*   perm = (const int*)d_in[2];     // [262144]      int32
    float*       out  = (float*)d_out;           // [262144,256]  fp32

    unsigned short* wbf = (unsigned short*)d_ws;                         // 2 MiB
    int*            inv = (int*)((char*)d_ws + (size_t)2 * 1024 * 1024); // 1 MiB

    prep_w  <<<1024, 256, 0, stream>>>(w, wbf);      // 16*256*256/4 float4s
    prep_inv<<<1024, 256, 0, stream>>>(perm, inv);   // NTOT threads
    gemm_scatter<<<KT * 256, 512, 0, stream>>>(x, wbf, inv, out);
}